// Round 6
// baseline (594.541 us; speedup 1.0000x reference)
//
#include <hip/hip_runtime.h>
#include <math.h>
#include <stdint.h>

// HashEmbedder, round 8: r7 structure + NON-TEMPORAL streaming accesses.
//
// Post-mortem r7: fused_tail was the straggler (~250-290 us inferred).
// Mechanism (visible in hash8's FETCH = 226 MB vs 128 MB ideal): streaming
// traffic (x reads, tmp read/write, out writes) flows through the same L2s
// that must keep the gather tables resident; LRU evicts table lines, which
// get re-fetched ~4x. In fused_tail this turns the 2.33 MB pair-table
// gathers into L3-latency misses. Fix: mark ALL streaming accesses
// non-temporal (`nt` flag) so table lines win the L2. One variable changed;
// grids/layouts/structure identical to r7.
//
//  - levels 8-15: hashed XCD-affine (level = blockIdx&7), table L2-resident.
//  - levels 6,7 : hashed parity-split (level = 6 + blockIdx&1), 4 XCDs each.
//  - levels 0-5 : even-pair 16B-cell compact tables (2.33 MB, resident in
//                 every XCD's L2), gathered point-major inside fused_tail.

#define NLEVELS 16
#define NFINE 10            // levels 6..15 staged in tmp
#define HASH_MASK 0x7FFFFu
#define TABLE_ENTRIES 524288  // 2^19 float2 entries per level

typedef float f32x2 __attribute__((ext_vector_type(2)));
typedef float f32x4 __attribute__((ext_vector_type(4)));

struct ResTable { float r[NLEVELS]; };
// Even-pair tables for levels 0-5: cell(i,j,m) = {v(i,j,2m), v(i,j,2m+1)},
// dim = D = res+2, Dm = ceil(D/2), off in 16B cells.
struct PairMeta { int dim[6]; int off[6]; };

// ---------------------------------------------------------------- hashed path
__device__ __forceinline__ float2 gather_one_level(
    const float* __restrict__ x, const float2* __restrict__ tbl,
    float bmin0, float bmin1, float bmin2,
    float bmax0, float bmax1, float bmax2,
    float res, int point)
{
    const float* xp = x + (size_t)point * 3;
    // Streaming: each line touched once per XCD -> nt.
    float x0 = __builtin_nontemporal_load(xp + 0);
    float x1 = __builtin_nontemporal_load(xp + 1);
    float x2 = __builtin_nontemporal_load(xp + 2);

    float xc0 = fminf(fmaxf(x0, bmin0), bmax0);
    float xc1 = fminf(fmaxf(x1, bmin1), bmax1);
    float xc2 = fminf(fmaxf(x2, bmin2), bmax2);

    float g0 = (bmax0 - bmin0) / res;
    float g1 = (bmax1 - bmin1) / res;
    float g2 = (bmax2 - bmin2) / res;

    float f0 = floorf((xc0 - bmin0) / g0);
    float f1 = floorf((xc1 - bmin1) / g1);
    float f2 = floorf((xc2 - bmin2) / g2);
    int b0 = (int)f0, b1 = (int)f1, b2 = (int)f2;

    float vmin0 = f0 * g0 + bmin0;
    float vmin1 = f1 * g1 + bmin1;
    float vmin2 = f2 * g2 + bmin2;
    float wx = (x0 - vmin0) / g0;
    float wy = (x1 - vmin1) / g1;
    float wz = (x2 - vmin2) / g2;

    uint32_t hx0 = (uint32_t)b0;
    uint32_t hx1 = (uint32_t)(b0 + 1);
    uint32_t hy0 = (uint32_t)b1 * 2654435761u;
    uint32_t hy1 = (uint32_t)(b1 + 1) * 2654435761u;
    uint32_t hz0 = (uint32_t)b2 * 805459861u;
    uint32_t hz1 = (uint32_t)(b2 + 1) * 805459861u;

    // Table gathers: CACHED (the thing nt protects).
    float2 v0 = tbl[(hx0 ^ hy0 ^ hz0) & HASH_MASK];
    float2 v1 = tbl[(hx0 ^ hy0 ^ hz1) & HASH_MASK];
    float2 v2 = tbl[(hx0 ^ hy1 ^ hz0) & HASH_MASK];
    float2 v3 = tbl[(hx0 ^ hy1 ^ hz1) & HASH_MASK];
    float2 v4 = tbl[(hx1 ^ hy0 ^ hz0) & HASH_MASK];
    float2 v5 = tbl[(hx1 ^ hy0 ^ hz1) & HASH_MASK];
    float2 v6 = tbl[(hx1 ^ hy1 ^ hz0) & HASH_MASK];
    float2 v7 = tbl[(hx1 ^ hy1 ^ hz1) & HASH_MASK];

    float omx = 1.0f - wx, omy = 1.0f - wy, omz = 1.0f - wz;

    float c00_0 = v0.x * omx + v4.x * wx;
    float c00_1 = v0.y * omx + v4.y * wx;
    float c01_0 = v1.x * omx + v5.x * wx;
    float c01_1 = v1.y * omx + v5.y * wx;
    float c10_0 = v2.x * omx + v6.x * wx;
    float c10_1 = v2.y * omx + v6.y * wx;
    float c11_0 = v3.x * omx + v7.x * wx;
    float c11_1 = v3.y * omx + v7.y * wx;

    float c0_0 = c00_0 * omy + c10_0 * wy;
    float c0_1 = c00_1 * omy + c10_1 * wy;
    float c1_0 = c01_0 * omy + c11_0 * wy;
    float c1_1 = c01_1 * omy + c11_1 * wy;

    float2 o;
    o.x = c0_0 * omz + c1_0 * wz;
    o.y = c0_1 * omz + c1_1 * wz;
    return o;
}

__device__ __forceinline__ void nt_store2(float2* p, float2 v) {
    f32x2 t = {v.x, v.y};
    __builtin_nontemporal_store(t, (f32x2*)p);
}

// 8 hashed levels, one per XCD slot (level = blockIdx&7 + base). Stores at
// tmp index (level - tmp_lo).
__global__ __launch_bounds__(256) void gather_hash8_kernel(
    const float* __restrict__ x,
    const float* __restrict__ emb,
    const float* __restrict__ bbox,
    float2* __restrict__ tmp,
    int n_points, int level_base, int tmp_lo, ResTable rt)
{
    int level = (blockIdx.x & 7) + level_base;
    int point = (blockIdx.x >> 3) * 256 + threadIdx.x;
    if (point >= n_points) return;

    float bmin0 = bbox[0], bmin1 = bbox[1], bmin2 = bbox[2];
    float bmax0 = bbox[3], bmax1 = bbox[4], bmax2 = bbox[5];

    const float2* tbl = (const float2*)emb + (size_t)level * TABLE_ENTRIES;
    float2 o = gather_one_level(x, tbl, bmin0, bmin1, bmin2,
                                bmax0, bmax1, bmax2, rt.r[level], point);
    nt_store2(&tmp[(size_t)(level - tmp_lo) * n_points + point], o);
}

// Levels 6,7 parity-split: 4 XCDs hold level 6's table, 4 hold level 7's.
__global__ __launch_bounds__(256) void gather_hash2_kernel(
    const float* __restrict__ x,
    const float* __restrict__ emb,
    const float* __restrict__ bbox,
    float2* __restrict__ tmp,
    int n_points, ResTable rt)
{
    int level = 6 + (blockIdx.x & 1);
    int point = (blockIdx.x >> 1) * 256 + threadIdx.x;
    if (point >= n_points) return;

    float bmin0 = bbox[0], bmin1 = bbox[1], bmin2 = bbox[2];
    float bmax0 = bbox[3], bmax1 = bbox[4], bmax2 = bbox[5];

    const float2* tbl = (const float2*)emb + (size_t)level * TABLE_ENTRIES;
    float2 o = gather_one_level(x, tbl, bmin0, bmin1, bmin2,
                                bmax0, bmax1, bmax2, rt.r[level], point);
    nt_store2(&tmp[(size_t)(level - 6) * n_points + point], o);
}

// ---------------------------------------------------------------- pair tables
// Build even-pair cells for levels 0-5. ~145K cells -> ~3 us.
__global__ __launch_bounds__(256) void build_pair_kernel(
    const float* __restrict__ emb,
    float4* __restrict__ pair,
    PairMeta pm, int total)
{
    int id = blockIdx.x * 256 + threadIdx.x;
    if (id >= total) return;

    int l = 0;
#pragma unroll
    for (int t = 1; t < 6; ++t)
        if (id >= pm.off[t]) l = t;
    int local = id - pm.off[l];
    int D = pm.dim[l];
    int Dm = (D + 1) >> 1;

    int m = local % Dm;
    int t2 = local / Dm;
    int j = t2 % D;
    int i = t2 / D;
    int k0 = 2 * m, k1 = 2 * m + 1;

    uint32_t hij = (uint32_t)i ^ ((uint32_t)j * 2654435761u);
    uint32_t h0 = (hij ^ ((uint32_t)k0 * 805459861u)) & HASH_MASK;
    uint32_t h1 = (hij ^ ((uint32_t)k1 * 805459861u)) & HASH_MASK;
    const float2* tbl = (const float2*)emb + (size_t)l * TABLE_ENTRIES;
    float2 a = tbl[h0];
    float2 b = tbl[h1];
    pair[id] = make_float4(a.x, a.y, b.x, b.y);
}

// ---------------------------------------------------------------- fused tail
// Point-major: gather levels 0-5 from the 2.33 MB pair tables (kept
// L2-resident by nt-marking all streaming traffic), read levels 6-15 from
// tmp (nt), LDS-transpose, nt float4 output + mask.
__global__ __launch_bounds__(256) void fused_tail_kernel(
    const float* __restrict__ x,
    const float4* __restrict__ pair,
    const float2* __restrict__ tmp,   // [NFINE][n_points]
    const float* __restrict__ bbox,
    float* __restrict__ out,
    float* __restrict__ mask,
    int n_points, PairMeta pm, ResTable rt)
{
    __shared__ float lds[256 * 33];

    const int tid = threadIdx.x;
    const int p0 = blockIdx.x * 256;
    const int p = p0 + tid;

    if (p < n_points) {
        float bmin0 = bbox[0], bmin1 = bbox[1], bmin2 = bbox[2];
        float bmax0 = bbox[3], bmax1 = bbox[4], bmax2 = bbox[5];

        const float* xp = x + (size_t)p * 3;
        float x0 = __builtin_nontemporal_load(xp + 0);
        float x1 = __builtin_nontemporal_load(xp + 1);
        float x2 = __builtin_nontemporal_load(xp + 2);
        bool keep = (x0 >= bmin0) & (x0 <= bmax0) &
                    (x1 >= bmin1) & (x1 <= bmax1) &
                    (x2 >= bmin2) & (x2 <= bmax2);
        __builtin_nontemporal_store(keep ? 1.0f : 0.0f, &mask[p]);

        float xc0 = fminf(fmaxf(x0, bmin0), bmax0);
        float xc1 = fminf(fmaxf(x1, bmin1), bmax1);
        float xc2 = fminf(fmaxf(x2, bmin2), bmax2);

#pragma unroll
        for (int l = 0; l < 6; ++l) {
            float res = rt.r[l];
            float g0 = (bmax0 - bmin0) / res;
            float g1 = (bmax1 - bmin1) / res;
            float g2 = (bmax2 - bmin2) / res;

            float f0 = floorf((xc0 - bmin0) / g0);
            float f1 = floorf((xc1 - bmin1) / g1);
            float f2 = floorf((xc2 - bmin2) / g2);
            int b0 = (int)f0, b1 = (int)f1, b2 = (int)f2;

            float vmin0 = f0 * g0 + bmin0;
            float vmin1 = f1 * g1 + bmin1;
            float vmin2 = f2 * g2 + bmin2;
            float wx = (x0 - vmin0) / g0;
            float wy = (x1 - vmin1) / g1;
            float wz = (x2 - vmin2) / g2;

            int D = pm.dim[l];
            int Dm = (D + 1) >> 1;
            const float4* tb = pair + pm.off[l];

            int m0 = b2 >> 1;
            int r00 = (b0 * D + b1) * Dm;
            int r01 = r00 + Dm;
            int r10 = r00 + D * Dm;
            int r11 = r10 + Dm;

            // Cached gathers (protected by nt on the streams).
            float4 a00 = tb[r00 + m0];
            float4 a01 = tb[r01 + m0];
            float4 a10 = tb[r10 + m0];
            float4 a11 = tb[r11 + m0];

            float2 v0, v1, v2, v3, v4, v5, v6, v7;
            if (b2 & 1) {
                int m1 = m0 + 1;
                float4 e00 = tb[r00 + m1];
                float4 e01 = tb[r01 + m1];
                float4 e10 = tb[r10 + m1];
                float4 e11 = tb[r11 + m1];
                v0 = make_float2(a00.z, a00.w); v1 = make_float2(e00.x, e00.y);
                v2 = make_float2(a01.z, a01.w); v3 = make_float2(e01.x, e01.y);
                v4 = make_float2(a10.z, a10.w); v5 = make_float2(e10.x, e10.y);
                v6 = make_float2(a11.z, a11.w); v7 = make_float2(e11.x, e11.y);
            } else {
                v0 = make_float2(a00.x, a00.y); v1 = make_float2(a00.z, a00.w);
                v2 = make_float2(a01.x, a01.y); v3 = make_float2(a01.z, a01.w);
                v4 = make_float2(a10.x, a10.y); v5 = make_float2(a10.z, a10.w);
                v6 = make_float2(a11.x, a11.y); v7 = make_float2(a11.z, a11.w);
            }

            float omx = 1.0f - wx, omy = 1.0f - wy, omz = 1.0f - wz;

            float c00_0 = v0.x * omx + v4.x * wx;
            float c00_1 = v0.y * omx + v4.y * wx;
            float c01_0 = v1.x * omx + v5.x * wx;
            float c01_1 = v1.y * omx + v5.y * wx;
            float c10_0 = v2.x * omx + v6.x * wx;
            float c10_1 = v2.y * omx + v6.y * wx;
            float c11_0 = v3.x * omx + v7.x * wx;
            float c11_1 = v3.y * omx + v7.y * wx;

            float c0_0 = c00_0 * omy + c10_0 * wy;
            float c0_1 = c00_1 * omy + c10_1 * wy;
            float c1_0 = c01_0 * omy + c11_0 * wy;
            float c1_1 = c01_1 * omy + c11_1 * wy;

            lds[tid * 33 + 2 * l]     = c0_0 * omz + c1_0 * wz;
            lds[tid * 33 + 2 * l + 1] = c0_1 * omz + c1_1 * wz;
        }

#pragma unroll
        for (int l = 0; l < NFINE; ++l) {
            f32x2 v = __builtin_nontemporal_load(
                (const f32x2*)&tmp[(size_t)l * n_points + p]);
            lds[tid * 33 + 12 + 2 * l]     = v.x;
            lds[tid * 33 + 12 + 2 * l + 1] = v.y;
        }
    }

    __syncthreads();

    int nblk = n_points - p0;
    if (nblk > 256) nblk = 256;
    const int nfloat4 = nblk * 8;
    float* dst = out + (size_t)p0 * 32;
#pragma unroll
    for (int j = 0; j < 8; ++j) {
        int v = j * 256 + tid;
        if (v < nfloat4) {
            int q = v >> 3;
            int k = (v & 7) << 2;
            const float* s = &lds[q * 33 + k];
            f32x4 val = {s[0], s[1], s[2], s[3]};
            __builtin_nontemporal_store(val, (f32x4*)(dst + v * 4));
        }
    }
}

// ---------------------------------------------------------------- mid tier
__global__ __launch_bounds__(256) void assemble_lds_kernel(
    const float* __restrict__ x,
    const float2* __restrict__ tmp,
    const float* __restrict__ bbox,
    float* __restrict__ out,
    float* __restrict__ mask,
    int n_points)
{
    __shared__ float lds[256 * 33];

    const int tid = threadIdx.x;
    const int p0 = blockIdx.x * 256;
    const int p = p0 + tid;

    if (p < n_points) {
#pragma unroll
        for (int l = 0; l < NLEVELS; ++l) {
            float2 v = tmp[(size_t)l * n_points + p];
            lds[tid * 33 + 2 * l]     = v.x;
            lds[tid * 33 + 2 * l + 1] = v.y;
        }
        float bmin0 = bbox[0], bmin1 = bbox[1], bmin2 = bbox[2];
        float bmax0 = bbox[3], bmax1 = bbox[4], bmax2 = bbox[5];
        const float* xp = x + (size_t)p * 3;
        float x0 = xp[0], x1 = xp[1], x2 = xp[2];
        bool keep = (x0 >= bmin0) & (x0 <= bmax0) &
                    (x1 >= bmin1) & (x1 <= bmax1) &
                    (x2 >= bmin2) & (x2 <= bmax2);
        mask[p] = keep ? 1.0f : 0.0f;
    }

    __syncthreads();

    int nblk = n_points - p0;
    if (nblk > 256) nblk = 256;
    const int nfloat4 = nblk * 8;
    float4* dst = (float4*)(out + (size_t)p0 * 32);
#pragma unroll
    for (int j = 0; j < 8; ++j) {
        int v = j * 256 + tid;
        if (v < nfloat4) {
            int q = v >> 3;
            int k = (v & 7) << 2;
            const float* s = &lds[q * 33 + k];
            dst[v] = make_float4(s[0], s[1], s[2], s[3]);
        }
    }
}

// ---------------------------------------------------------------- fallback
__global__ __launch_bounds__(256) void hash_embed_direct_kernel(
    const float* __restrict__ x,
    const float* __restrict__ emb,
    const float* __restrict__ bbox,
    float* __restrict__ out,
    float* __restrict__ mask,
    int n_points, ResTable rt)
{
    int tid = blockIdx.x * 256 + threadIdx.x;
    int point = tid >> 4;
    int level = tid & 15;
    if (point >= n_points) return;

    float bmin0 = bbox[0], bmin1 = bbox[1], bmin2 = bbox[2];
    float bmax0 = bbox[3], bmax1 = bbox[4], bmax2 = bbox[5];

    if (level == 0) {
        const float* xp = x + (size_t)point * 3;
        float x0 = xp[0], x1 = xp[1], x2 = xp[2];
        bool keep = (x0 >= bmin0) & (x0 <= bmax0) &
                    (x1 >= bmin1) & (x1 <= bmax1) &
                    (x2 >= bmin2) & (x2 <= bmax2);
        mask[point] = keep ? 1.0f : 0.0f;
    }

    const float2* tbl = (const float2*)emb + (size_t)level * TABLE_ENTRIES;
    float2 o = gather_one_level(x, tbl, bmin0, bmin1, bmin2,
                                bmax0, bmax1, bmax2, rt.r[level], point);
    *(float2*)(out + (size_t)point * 32 + level * 2) = o;
}

// ---------------------------------------------------------------- launch
extern "C" void kernel_launch(void* const* d_in, const int* in_sizes, int n_in,
                              void* d_out, int out_size, void* d_ws, size_t ws_size,
                              hipStream_t stream) {
    const float* x    = (const float*)d_in[0];
    const float* emb  = (const float*)d_in[1];
    const float* bbox = (const float*)d_in[2];
    int n_points = in_sizes[0] / 3;

    float* out  = (float*)d_out;
    float* mask = out + (size_t)n_points * 32;

    // Host-side double libm matches numpy's resolution floor (levels
    // 3/6/9/12/15 are ulp-close to exact powers of two).
    ResTable rt;
    double b = exp((log(512.0) - log(16.0)) / 15.0);
    for (int l = 0; l < NLEVELS; ++l)
        rt.r[l] = (float)floor(16.0 * pow(b, (double)l));

    // Even-pair geometry for levels 0-5: D = res+2 (corners reach res+1 at
    // the clamp boundary), Dm = ceil(D/2). Total ~145K cells = 2.33 MB.
    PairMeta pm;
    int total_cells = 0;
    for (int l = 0; l < 6; ++l) {
        int D = (int)rt.r[l] + 2;
        pm.dim[l] = D;
        pm.off[l] = total_cells;
        total_cells += D * D * ((D + 1) >> 1);
    }

    size_t tmp10_bytes = (size_t)n_points * NFINE * sizeof(float2);
    size_t tmp16_bytes = (size_t)n_points * NLEVELS * sizeof(float2);
    size_t pair_bytes  = (size_t)total_cells * sizeof(float4);

    int chunks = (n_points + 255) / 256;

    if (ws_size >= tmp10_bytes + pair_bytes) {
        float2* tmp  = (float2*)d_ws;
        float4* pair = (float4*)((char*)d_ws + tmp10_bytes);

        int pre_blocks = (total_cells + 255) / 256;
        hipLaunchKernelGGL(build_pair_kernel, dim3(pre_blocks), dim3(256),
                           0, stream, emb, pair, pm, total_cells);

        // Levels 8-15: one 4 MB table per XCD (proven 218 us floor).
        hipLaunchKernelGGL(gather_hash8_kernel, dim3(chunks * 8), dim3(256),
                           0, stream, x, emb, bbox, tmp, n_points, 8, 6, rt);
        // Levels 6,7: parity-split across XCDs.
        hipLaunchKernelGGL(gather_hash2_kernel, dim3(chunks * 2), dim3(256),
                           0, stream, x, emb, bbox, tmp, n_points, rt);
        // Levels 0-5 gather (L2-resident pair tables) + transpose + output.
        hipLaunchKernelGGL(fused_tail_kernel, dim3(chunks), dim3(256),
                           0, stream, x, pair, tmp, bbox, out, mask,
                           n_points, pm, rt);
    } else if (ws_size >= tmp16_bytes) {
        float2* tmp = (float2*)d_ws;
        dim3 grid(chunks * 8);
        hipLaunchKernelGGL(gather_hash8_kernel, grid, dim3(256), 0, stream,
                           x, emb, bbox, tmp, n_points, 0, 0, rt);
        hipLaunchKernelGGL(gather_hash8_kernel, grid, dim3(256), 0, stream,
                           x, emb, bbox, tmp, n_points, 8, 0, rt);
        hipLaunchKernelGGL(assemble_lds_kernel, dim3(chunks), dim3(256), 0,
                           stream, x, tmp, bbox, out, mask, n_points);
    } else {
        long long total = (long long)n_points * NLEVELS;
        int blocks = (int)((total + 255) / 256);
        hipLaunchKernelGGL(hash_embed_direct_kernel, dim3(blocks), dim3(256), 0,
                           stream, x, emb, bbox, out, mask, n_points, rt);
    }
}

// Round 7
// 552.867 us; speedup vs baseline: 1.0754x; 1.0754x over previous
//
#include <hip/hip_runtime.h>
#include <math.h>
#include <stdint.h>

// HashEmbedder, round 9: merged hash dispatch + dup-pair coarse tables +
// tmp register-prefetch in the fused tail.
//
// Post-mortem r8: ~114 us of the wall is FIXED harness overhead (proven by
// r3: single kernel 680 us counter vs 794 wall). Controllable kernel time
// ~480 us vs ~390-410 floor. hash8 is at its request floor (15.3
// req/cyc/XCD). Changes:
//  1) hash levels 8-15 AND 6-7 in ONE dispatch (appended segment, parity
//     preserved since chunks*8 % 8 == 0) -> one less gap + tail overlap.
//  2) levels 0-3: dup-pair cells {v(k),v(k+1)} at every k -> always 4
//     aligned 16B loads; levels 4-5 half-pair (pair set 2.93 MB < 4MB L2).
//  3) fused tail prefetches all 10 tmp levels into registers first.

#define NLEVELS 16
#define NFINE 10            // levels 6..15 staged in tmp
#define HASH_MASK 0x7FFFFu
#define TABLE_ENTRIES 524288  // 2^19 float2 entries per level

typedef float f32x2 __attribute__((ext_vector_type(2)));
typedef float f32x4 __attribute__((ext_vector_type(4)));

struct ResTable { float r[NLEVELS]; };
// Pair tables for levels 0-5. Levels 0-3: dup layout, cell(i,j,k) =
// {v(k),v(k+1)}, D^3 cells. Levels 4-5: half-pair, cell(i,j,m) =
// {v(2m),v(2m+1)}, D^2*ceil(D/2) cells. dim = D = res+2, off in 16B cells.
struct PairMeta { int dim[6]; int off[6]; };

// ---------------------------------------------------------------- hashed path
__device__ __forceinline__ float2 gather_one_level(
    const float* __restrict__ x, const float2* __restrict__ tbl,
    float bmin0, float bmin1, float bmin2,
    float bmax0, float bmax1, float bmax2,
    float res, int point)
{
    const float* xp = x + (size_t)point * 3;
    float x0 = __builtin_nontemporal_load(xp + 0);
    float x1 = __builtin_nontemporal_load(xp + 1);
    float x2 = __builtin_nontemporal_load(xp + 2);

    float xc0 = fminf(fmaxf(x0, bmin0), bmax0);
    float xc1 = fminf(fmaxf(x1, bmin1), bmax1);
    float xc2 = fminf(fmaxf(x2, bmin2), bmax2);

    float g0 = (bmax0 - bmin0) / res;
    float g1 = (bmax1 - bmin1) / res;
    float g2 = (bmax2 - bmin2) / res;

    float f0 = floorf((xc0 - bmin0) / g0);
    float f1 = floorf((xc1 - bmin1) / g1);
    float f2 = floorf((xc2 - bmin2) / g2);
    int b0 = (int)f0, b1 = (int)f1, b2 = (int)f2;

    float vmin0 = f0 * g0 + bmin0;
    float vmin1 = f1 * g1 + bmin1;
    float vmin2 = f2 * g2 + bmin2;
    float wx = (x0 - vmin0) / g0;
    float wy = (x1 - vmin1) / g1;
    float wz = (x2 - vmin2) / g2;

    uint32_t hx0 = (uint32_t)b0;
    uint32_t hx1 = (uint32_t)(b0 + 1);
    uint32_t hy0 = (uint32_t)b1 * 2654435761u;
    uint32_t hy1 = (uint32_t)(b1 + 1) * 2654435761u;
    uint32_t hz0 = (uint32_t)b2 * 805459861u;
    uint32_t hz1 = (uint32_t)(b2 + 1) * 805459861u;

    // Table gathers: cached (nt on streams protects these).
    float2 v0 = tbl[(hx0 ^ hy0 ^ hz0) & HASH_MASK];
    float2 v1 = tbl[(hx0 ^ hy0 ^ hz1) & HASH_MASK];
    float2 v2 = tbl[(hx0 ^ hy1 ^ hz0) & HASH_MASK];
    float2 v3 = tbl[(hx0 ^ hy1 ^ hz1) & HASH_MASK];
    float2 v4 = tbl[(hx1 ^ hy0 ^ hz0) & HASH_MASK];
    float2 v5 = tbl[(hx1 ^ hy0 ^ hz1) & HASH_MASK];
    float2 v6 = tbl[(hx1 ^ hy1 ^ hz0) & HASH_MASK];
    float2 v7 = tbl[(hx1 ^ hy1 ^ hz1) & HASH_MASK];

    float omx = 1.0f - wx, omy = 1.0f - wy, omz = 1.0f - wz;

    float c00_0 = v0.x * omx + v4.x * wx;
    float c00_1 = v0.y * omx + v4.y * wx;
    float c01_0 = v1.x * omx + v5.x * wx;
    float c01_1 = v1.y * omx + v5.y * wx;
    float c10_0 = v2.x * omx + v6.x * wx;
    float c10_1 = v2.y * omx + v6.y * wx;
    float c11_0 = v3.x * omx + v7.x * wx;
    float c11_1 = v3.y * omx + v7.y * wx;

    float c0_0 = c00_0 * omy + c10_0 * wy;
    float c0_1 = c00_1 * omy + c10_1 * wy;
    float c1_0 = c01_0 * omy + c11_0 * wy;
    float c1_1 = c01_1 * omy + c11_1 * wy;

    float2 o;
    o.x = c0_0 * omz + c1_0 * wz;
    o.y = c0_1 * omz + c1_1 * wz;
    return o;
}

__device__ __forceinline__ void nt_store2(float2* p, float2 v) {
    f32x2 t = {v.x, v.y};
    __builtin_nontemporal_store(t, (f32x2*)p);
}

// Merged hashed levels. Blocks [0, chunks8): level = 8 + (b&7) (one 4 MB
// table per XCD). Blocks [chunks8, chunks8 + chunks2): level = 6 + (c&1)
// (parity-split: 4 XCDs per table; chunks8 % 8 == 0 preserves the mapping).
__global__ __launch_bounds__(256) void gather_hash_kernel(
    const float* __restrict__ x,
    const float* __restrict__ emb,
    const float* __restrict__ bbox,
    float2* __restrict__ tmp,   // [NFINE][n_points], level-6 major
    int n_points, int chunks8, ResTable rt)
{
    int b = blockIdx.x;
    int level, pchunk;
    if (b < chunks8) { level = 8 + (b & 7); pchunk = b >> 3; }
    else             { int c = b - chunks8; level = 6 + (c & 1); pchunk = c >> 1; }
    int point = pchunk * 256 + threadIdx.x;
    if (point >= n_points) return;

    float bmin0 = bbox[0], bmin1 = bbox[1], bmin2 = bbox[2];
    float bmax0 = bbox[3], bmax1 = bbox[4], bmax2 = bbox[5];

    const float2* tbl = (const float2*)emb + (size_t)level * TABLE_ENTRIES;
    float2 o = gather_one_level(x, tbl, bmin0, bmin1, bmin2,
                                bmax0, bmax1, bmax2, rt.r[level], point);
    nt_store2(&tmp[(size_t)(level - 6) * n_points + point], o);
}

// Level-affine 8-slot gather (mid-tier fallback path).
__global__ __launch_bounds__(256) void gather_level_kernel(
    const float* __restrict__ x,
    const float* __restrict__ emb,
    const float* __restrict__ bbox,
    float2* __restrict__ tmp,   // [NLEVELS][n_points]
    int n_points, int level_base, ResTable rt)
{
    int level = (blockIdx.x & 7) + level_base;
    int point = (blockIdx.x >> 3) * 256 + threadIdx.x;
    if (point >= n_points) return;

    float bmin0 = bbox[0], bmin1 = bbox[1], bmin2 = bbox[2];
    float bmax0 = bbox[3], bmax1 = bbox[4], bmax2 = bbox[5];

    const float2* tbl = (const float2*)emb + (size_t)level * TABLE_ENTRIES;
    float2 o = gather_one_level(x, tbl, bmin0, bmin1, bmin2,
                                bmax0, bmax1, bmax2, rt.r[level], point);
    nt_store2(&tmp[(size_t)level * n_points + point], o);
}

// ---------------------------------------------------------------- pair tables
// Levels 0-3: dup (D^3 cells, k0=k, k1=k+1; k=D-1 stores unused garbage —
// b2 <= D-2 so it is never read). Levels 4-5: half-pair.
__global__ __launch_bounds__(256) void build_pair_kernel(
    const float* __restrict__ emb,
    float4* __restrict__ pair,
    PairMeta pm, int total)
{
    int id = blockIdx.x * 256 + threadIdx.x;
    if (id >= total) return;

    int l = 0;
#pragma unroll
    for (int t = 1; t < 6; ++t)
        if (id >= pm.off[t]) l = t;
    int local = id - pm.off[l];
    int D = pm.dim[l];

    int i, j, k0, k1;
    if (l < 4) {
        int k = local % D;
        int t2 = local / D;
        j = t2 % D; i = t2 / D;
        k0 = k; k1 = k + 1;
    } else {
        int Dm = (D + 1) >> 1;
        int m = local % Dm;
        int t2 = local / Dm;
        j = t2 % D; i = t2 / D;
        k0 = 2 * m; k1 = 2 * m + 1;
    }

    uint32_t hij = (uint32_t)i ^ ((uint32_t)j * 2654435761u);
    uint32_t h0 = (hij ^ ((uint32_t)k0 * 805459861u)) & HASH_MASK;
    uint32_t h1 = (hij ^ ((uint32_t)k1 * 805459861u)) & HASH_MASK;
    const float2* tbl = (const float2*)emb + (size_t)l * TABLE_ENTRIES;
    float2 a = tbl[h0];
    float2 b = tbl[h1];
    pair[id] = make_float4(a.x, a.y, b.x, b.y);
}

// ---------------------------------------------------------------- fused tail
// Point-major: prefetch tmp levels 6-15 into registers (latency hidden
// under coarse gathers), gather levels 0-5 from the 2.93 MB pair tables
// (L2-resident everywhere; nt streams protect them), LDS-transpose,
// coalesced nt float4 output + mask.
__global__ __launch_bounds__(256) void fused_tail_kernel(
    const float* __restrict__ x,
    const float4* __restrict__ pair,
    const float2* __restrict__ tmp,   // [NFINE][n_points]
    const float* __restrict__ bbox,
    float* __restrict__ out,
    float* __restrict__ mask,
    int n_points, PairMeta pm, ResTable rt)
{
    __shared__ float lds[256 * 33];

    const int tid = threadIdx.x;
    const int p0 = blockIdx.x * 256;
    const int p = p0 + tid;

    if (p < n_points) {
        float bmin0 = bbox[0], bmin1 = bbox[1], bmin2 = bbox[2];
        float bmax0 = bbox[3], bmax1 = bbox[4], bmax2 = bbox[5];

        const float* xp = x + (size_t)p * 3;
        float x0 = __builtin_nontemporal_load(xp + 0);
        float x1 = __builtin_nontemporal_load(xp + 1);
        float x2 = __builtin_nontemporal_load(xp + 2);

        // Issue all 10 tmp reads up front; consumed at the end.
        f32x2 tv[NFINE];
#pragma unroll
        for (int l = 0; l < NFINE; ++l)
            tv[l] = __builtin_nontemporal_load(
                (const f32x2*)&tmp[(size_t)l * n_points + p]);

        bool keep = (x0 >= bmin0) & (x0 <= bmax0) &
                    (x1 >= bmin1) & (x1 <= bmax1) &
                    (x2 >= bmin2) & (x2 <= bmax2);
        __builtin_nontemporal_store(keep ? 1.0f : 0.0f, &mask[p]);

        float xc0 = fminf(fmaxf(x0, bmin0), bmax0);
        float xc1 = fminf(fmaxf(x1, bmin1), bmax1);
        float xc2 = fminf(fmaxf(x2, bmin2), bmax2);

#pragma unroll
        for (int l = 0; l < 6; ++l) {
            float res = rt.r[l];
            float g0 = (bmax0 - bmin0) / res;
            float g1 = (bmax1 - bmin1) / res;
            float g2 = (bmax2 - bmin2) / res;

            float f0 = floorf((xc0 - bmin0) / g0);
            float f1 = floorf((xc1 - bmin1) / g1);
            float f2 = floorf((xc2 - bmin2) / g2);
            int b0 = (int)f0, b1 = (int)f1, b2 = (int)f2;

            float vmin0 = f0 * g0 + bmin0;
            float vmin1 = f1 * g1 + bmin1;
            float vmin2 = f2 * g2 + bmin2;
            float wx = (x0 - vmin0) / g0;
            float wy = (x1 - vmin1) / g1;
            float wz = (x2 - vmin2) / g2;

            int D = pm.dim[l];
            const float4* tb = pair + pm.off[l];

            float2 v0, v1, v2, v3, v4, v5, v6, v7;
            if (l < 4) {
                // Dup layout: 4 aligned 16B loads, always.
                int c = (b0 * D + b1) * D + b2;
                int dj = D, di = D * D;
                float4 a00 = tb[c];
                float4 a01 = tb[c + dj];
                float4 a10 = tb[c + di];
                float4 a11 = tb[c + di + dj];
                v0 = make_float2(a00.x, a00.y); v1 = make_float2(a00.z, a00.w);
                v2 = make_float2(a01.x, a01.y); v3 = make_float2(a01.z, a01.w);
                v4 = make_float2(a10.x, a10.y); v5 = make_float2(a10.z, a10.w);
                v6 = make_float2(a11.x, a11.y); v7 = make_float2(a11.z, a11.w);
            } else {
                // Half-pair layout.
                int Dm = (D + 1) >> 1;
                int m0 = b2 >> 1;
                int r00 = (b0 * D + b1) * Dm;
                int r01 = r00 + Dm;
                int r10 = r00 + D * Dm;
                int r11 = r10 + Dm;

                float4 a00 = tb[r00 + m0];
                float4 a01 = tb[r01 + m0];
                float4 a10 = tb[r10 + m0];
                float4 a11 = tb[r11 + m0];

                if (b2 & 1) {
                    int m1 = m0 + 1;
                    float4 e00 = tb[r00 + m1];
                    float4 e01 = tb[r01 + m1];
                    float4 e10 = tb[r10 + m1];
                    float4 e11 = tb[r11 + m1];
                    v0 = make_float2(a00.z, a00.w); v1 = make_float2(e00.x, e00.y);
                    v2 = make_float2(a01.z, a01.w); v3 = make_float2(e01.x, e01.y);
                    v4 = make_float2(a10.z, a10.w); v5 = make_float2(e10.x, e10.y);
                    v6 = make_float2(a11.z, a11.w); v7 = make_float2(e11.x, e11.y);
                } else {
                    v0 = make_float2(a00.x, a00.y); v1 = make_float2(a00.z, a00.w);
                    v2 = make_float2(a01.x, a01.y); v3 = make_float2(a01.z, a01.w);
                    v4 = make_float2(a10.x, a10.y); v5 = make_float2(a10.z, a10.w);
                    v6 = make_float2(a11.x, a11.y); v7 = make_float2(a11.z, a11.w);
                }
            }

            float omx = 1.0f - wx, omy = 1.0f - wy, omz = 1.0f - wz;

            float c00_0 = v0.x * omx + v4.x * wx;
            float c00_1 = v0.y * omx + v4.y * wx;
            float c01_0 = v1.x * omx + v5.x * wx;
            float c01_1 = v1.y * omx + v5.y * wx;
            float c10_0 = v2.x * omx + v6.x * wx;
            float c10_1 = v2.y * omx + v6.y * wx;
            float c11_0 = v3.x * omx + v7.x * wx;
            float c11_1 = v3.y * omx + v7.y * wx;

            float c0_0 = c00_0 * omy + c10_0 * wy;
            float c0_1 = c00_1 * omy + c10_1 * wy;
            float c1_0 = c01_0 * omy + c11_0 * wy;
            float c1_1 = c01_1 * omy + c11_1 * wy;

            lds[tid * 33 + 2 * l]     = c0_0 * omz + c1_0 * wz;
            lds[tid * 33 + 2 * l + 1] = c0_1 * omz + c1_1 * wz;
        }

#pragma unroll
        for (int l = 0; l < NFINE; ++l) {
            lds[tid * 33 + 12 + 2 * l]     = tv[l].x;
            lds[tid * 33 + 12 + 2 * l + 1] = tv[l].y;
        }
    }

    __syncthreads();

    int nblk = n_points - p0;
    if (nblk > 256) nblk = 256;
    const int nfloat4 = nblk * 8;
    float* dst = out + (size_t)p0 * 32;
#pragma unroll
    for (int j = 0; j < 8; ++j) {
        int v = j * 256 + tid;
        if (v < nfloat4) {
            int q = v >> 3;
            int k = (v & 7) << 2;
            const float* s = &lds[q * 33 + k];
            f32x4 val = {s[0], s[1], s[2], s[3]};
            __builtin_nontemporal_store(val, (f32x4*)(dst + v * 4));
        }
    }
}

// ---------------------------------------------------------------- mid tier
__global__ __launch_bounds__(256) void assemble_lds_kernel(
    const float* __restrict__ x,
    const float2* __restrict__ tmp,
    const float* __restrict__ bbox,
    float* __restrict__ out,
    float* __restrict__ mask,
    int n_points)
{
    __shared__ float lds[256 * 33];

    const int tid = threadIdx.x;
    const int p0 = blockIdx.x * 256;
    const int p = p0 + tid;

    if (p < n_points) {
#pragma unroll
        for (int l = 0; l < NLEVELS; ++l) {
            float2 v = tmp[(size_t)l * n_points + p];
            lds[tid * 33 + 2 * l]     = v.x;
            lds[tid * 33 + 2 * l + 1] = v.y;
        }
        float bmin0 = bbox[0], bmin1 = bbox[1], bmin2 = bbox[2];
        float bmax0 = bbox[3], bmax1 = bbox[4], bmax2 = bbox[5];
        const float* xp = x + (size_t)p * 3;
        float x0 = xp[0], x1 = xp[1], x2 = xp[2];
        bool keep = (x0 >= bmin0) & (x0 <= bmax0) &
                    (x1 >= bmin1) & (x1 <= bmax1) &
                    (x2 >= bmin2) & (x2 <= bmax2);
        mask[p] = keep ? 1.0f : 0.0f;
    }

    __syncthreads();

    int nblk = n_points - p0;
    if (nblk > 256) nblk = 256;
    const int nfloat4 = nblk * 8;
    float4* dst = (float4*)(out + (size_t)p0 * 32);
#pragma unroll
    for (int j = 0; j < 8; ++j) {
        int v = j * 256 + tid;
        if (v < nfloat4) {
            int q = v >> 3;
            int k = (v & 7) << 2;
            const float* s = &lds[q * 33 + k];
            dst[v] = make_float4(s[0], s[1], s[2], s[3]);
        }
    }
}

// ---------------------------------------------------------------- fallback
__global__ __launch_bounds__(256) void hash_embed_direct_kernel(
    const float* __restrict__ x,
    const float* __restrict__ emb,
    const float* __restrict__ bbox,
    float* __restrict__ out,
    float* __restrict__ mask,
    int n_points, ResTable rt)
{
    int tid = blockIdx.x * 256 + threadIdx.x;
    int point = tid >> 4;
    int level = tid & 15;
    if (point >= n_points) return;

    float bmin0 = bbox[0], bmin1 = bbox[1], bmin2 = bbox[2];
    float bmax0 = bbox[3], bmax1 = bbox[4], bmax2 = bbox[5];

    if (level == 0) {
        const float* xp = x + (size_t)point * 3;
        float x0 = xp[0], x1 = xp[1], x2 = xp[2];
        bool keep = (x0 >= bmin0) & (x0 <= bmax0) &
                    (x1 >= bmin1) & (x1 <= bmax1) &
                    (x2 >= bmin2) & (x2 <= bmax2);
        mask[point] = keep ? 1.0f : 0.0f;
    }

    const float2* tbl = (const float2*)emb + (size_t)level * TABLE_ENTRIES;
    float2 o = gather_one_level(x, tbl, bmin0, bmin1, bmin2,
                                bmax0, bmax1, bmax2, rt.r[level], point);
    *(float2*)(out + (size_t)point * 32 + level * 2) = o;
}

// ---------------------------------------------------------------- launch
extern "C" void kernel_launch(void* const* d_in, const int* in_sizes, int n_in,
                              void* d_out, int out_size, void* d_ws, size_t ws_size,
                              hipStream_t stream) {
    const float* x    = (const float*)d_in[0];
    const float* emb  = (const float*)d_in[1];
    const float* bbox = (const float*)d_in[2];
    int n_points = in_sizes[0] / 3;

    float* out  = (float*)d_out;
    float* mask = out + (size_t)n_points * 32;

    // Host-side double libm matches numpy's resolution floor (levels
    // 3/6/9/12/15 are ulp-close to exact powers of two).
    ResTable rt;
    double b = exp((log(512.0) - log(16.0)) / 15.0);
    for (int l = 0; l < NLEVELS; ++l)
        rt.r[l] = (float)floor(16.0 * pow(b, (double)l));

    // Pair geometry: D = res+2 (corners reach res+1 at the clamp boundary).
    // Levels 0-3 dup (D^3), 4-5 half-pair (D^2*ceil(D/2)). Total 2.93 MB.
    PairMeta pm;
    int total_cells = 0;
    for (int l = 0; l < 6; ++l) {
        int D = (int)rt.r[l] + 2;
        pm.dim[l] = D;
        pm.off[l] = total_cells;
        total_cells += (l < 4) ? D * D * D : D * D * ((D + 1) >> 1);
    }

    size_t tmp10_bytes = (size_t)n_points * NFINE * sizeof(float2);
    size_t tmp16_bytes = (size_t)n_points * NLEVELS * sizeof(float2);
    size_t pair_bytes  = (size_t)total_cells * sizeof(float4);

    int chunks = (n_points + 255) / 256;

    if (ws_size >= tmp10_bytes + pair_bytes) {
        float2* tmp  = (float2*)d_ws;
        float4* pair = (float4*)((char*)d_ws + tmp10_bytes);

        int pre_blocks = (total_cells + 255) / 256;
        hipLaunchKernelGGL(build_pair_kernel, dim3(pre_blocks), dim3(256),
                           0, stream, emb, pair, pm, total_cells);

        // Levels 8-15 (XCD-affine) + levels 6,7 (parity-split), one dispatch.
        int chunks8 = chunks * 8;
        hipLaunchKernelGGL(gather_hash_kernel,
                           dim3(chunks8 + chunks * 2), dim3(256),
                           0, stream, x, emb, bbox, tmp, n_points, chunks8, rt);

        // Levels 0-5 gather (L2-resident pair tables) + transpose + output.
        hipLaunchKernelGGL(fused_tail_kernel, dim3(chunks), dim3(256),
                           0, stream, x, pair, tmp, bbox, out, mask,
                           n_points, pm, rt);
    } else if (ws_size >= tmp16_bytes) {
        float2* tmp = (float2*)d_ws;
        dim3 grid(chunks * 8);
        hipLaunchKernelGGL(gather_level_kernel, grid, dim3(256), 0, stream,
                           x, emb, bbox, tmp, n_points, 0, rt);
        hipLaunchKernelGGL(gather_level_kernel, grid, dim3(256), 0, stream,
                           x, emb, bbox, tmp, n_points, 8, rt);
        hipLaunchKernelGGL(assemble_lds_kernel, dim3(chunks), dim3(256), 0,
                           stream, x, tmp, bbox, out, mask, n_points);
    } else {
        long long total = (long long)n_points * NLEVELS;
        int blocks = (int)((total + 255) / 256);
        hipLaunchKernelGGL(hash_embed_direct_kernel, dim3(blocks), dim3(256), 0,
                           stream, x, emb, bbox, out, mask, n_points, rt);
    }
}